// Round 2
// baseline (539.901 us; speedup 1.0000x reference)
//
#include <hip/hip_runtime.h>
#include <cstdint>
#include <cstddef>

#define B_TOK 8192
#define HDIM  2048
#define CDIM  256
#define KHV   4096   // 2*H
#define N3H   6144   // 3*H
#define DT_C  0.1f

typedef __bf16 bf16x8 __attribute__((ext_vector_type(8)));
typedef float  f32x4  __attribute__((ext_vector_type(4)));

typedef __attribute__((address_space(1))) void as1_void;
typedef __attribute__((address_space(3))) void as3_void;

// async global->LDS, 16B per lane; LDS dst = wave-uniform base + lane*16
__device__ __forceinline__ void g2l16(const void* g, void* l) {
    __builtin_amdgcn_global_load_lds((as1_void*)(void*)(uintptr_t)(g),
                                     (as3_void*)l, 16, 0, 0);
}

__device__ __forceinline__ unsigned short f2bf(float f) {
    unsigned int u = __float_as_uint(f);
    u += 0x7fffu + ((u >> 16) & 1u);   // RNE
    return (unsigned short)(u >> 16);
}

__device__ __forceinline__ float bf2f(unsigned short s) {
    return __uint_as_float((unsigned int)s << 16);
}

// fast sigmoid: v_exp + v_rcp (no full-precision divide)
__device__ __forceinline__ float fsigmoid(float x) {
    return __builtin_amdgcn_rcpf(1.f + __expf(-x));
}
// fast softplus: max(x,0) + ln2*log2(1+exp(-|x|)), all native v_exp/v_log
__device__ __forceinline__ float fsoftplus(float x) {
    float t = __expf(-fabsf(x));
    return fmaxf(x, 0.f) + 0.69314718056f * __log2f(1.f + t);
}

// ---------------- K0: fp32 -> bf16 conversion (hv concat + weights) -------
// compiler (__bf16) casts -> v_cvt_pk_bf16_f32 (1 instr / 2 elems) instead of
// 3-VALU manual RNE; kernel was VALU-bound, not BW-bound.
__global__ void k_convert(const float* __restrict__ hp, const float* __restrict__ vp,
                          const float* __restrict__ Win, const float* __restrict__ Wout,
                          const float* __restrict__ Wmu,
                          ushort4* __restrict__ hv_b, ushort4* __restrict__ Wmu_b,
                          ushort4* __restrict__ Wout_b, ushort4* __restrict__ Win_b)
{
    const int HV_V   = B_TOK * KHV / 4;    // 8388608 vec4
    const int WMU_V  = HDIM * HDIM / 4;    // 1048576
    const int WOUT_V = N3H * CDIM / 4;     // 393216
    const int WIN_V  = CDIM * KHV / 4;     // 262144
    const int TOT    = HV_V + WMU_V + WOUT_V + WIN_V;
    for (int i = blockIdx.x * blockDim.x + threadIdx.x; i < TOT;
         i += gridDim.x * blockDim.x) {
        float4 x;
        ushort4* dst;
        if (i < HV_V) {
            int b  = i >> 10;          // row (4096/4 = 1024 vec4 per row)
            int c4 = i & 1023;
            x = (c4 < 512) ? ((const float4*)hp)[b * 512 + c4]
                           : ((const float4*)vp)[b * 512 + (c4 - 512)];
            dst = hv_b + i;
        } else if (i < HV_V + WMU_V) {
            int j = i - HV_V;
            x = ((const float4*)Wmu)[j];
            dst = Wmu_b + j;
        } else if (i < HV_V + WMU_V + WOUT_V) {
            int j = i - (HV_V + WMU_V);
            x = ((const float4*)Wout)[j];
            dst = Wout_b + j;
        } else {
            int j = i - (HV_V + WMU_V + WOUT_V);
            x = ((const float4*)Win)[j];
            dst = Win_b + j;
        }
        ushort4 o;
        o.x = __builtin_bit_cast(unsigned short, (__bf16)x.x);
        o.y = __builtin_bit_cast(unsigned short, (__bf16)x.y);
        o.z = __builtin_bit_cast(unsigned short, (__bf16)x.z);
        o.w = __builtin_bit_cast(unsigned short, (__bf16)x.w);
        *dst = o;
    }
}

// ---------------- K_mid: fat kernel = gemm1 + gemm3, 2-phase pipelined ----
// gemm1 (b%3==0, 512 blocks): ctrl = silu(hv @ Win^T + b_in), 64x64, BK=64
//   BK=64 row stride = 128B -> 16-way bank conflict if linear; XOR swizzle
//   chunk^=(row&7) on both the g2l16 SOURCE and the ds_read (rule #21).
// gemm3 (else, 1024 blocks): mu_ctx = mu + h @ Wmu^T, 128x128, BK=32
//   (64B row stride is already minimal-aliasing -> no swizzle).
// Interleaved b%3 mapping: every CU co-hosts both work types (m114 overlap).
// K-loop: T3-minimal: stage(next buf) -> compute(cur) -> ONE __syncthreads
// (its vmcnt0+lgkmcnt0 drain is hidden under compute).
__global__ __launch_bounds__(256, 2)
void k_mid(const unsigned short* __restrict__ hvb,
           const unsigned short* __restrict__ Winb,
           const unsigned short* __restrict__ Wmub,
           const float* __restrict__ b_in,
           const float* __restrict__ mu,
           unsigned short* __restrict__ ctrl,
           float* __restrict__ outmu)
{
    __shared__ unsigned short sA[2][4096];   // 8KB/buf: 64x64 (g1) or 128x32 (g3)
    __shared__ unsigned short sB[2][4096];
    const int tid  = threadIdx.x;
    const int wid  = tid >> 6;
    const int lane = tid & 63;
    const int quad = lane >> 4;
    const int l15  = lane & 15;
    const int wm   = wid >> 1, wn = wid & 1;

    const unsigned int bidx = blockIdx.x;
    const unsigned int r3   = bidx % 3u;

    if (r3 == 0u) {
        // ----- gemm1: 64x64 tile, BK=64, swizzled LDS -----
        const int g1 = (int)(bidx / 3u);           // 0..511
        const int s  = (g1 & 7) * 64 + (g1 >> 3);  // same-XCD groups share A-panel
        const int bm = (s >> 2) * 64;
        const int bn = (s & 3) * 64;

        f32x4 acc[2][2];
#pragma unroll
        for (int a = 0; a < 2; ++a)
#pragma unroll
            for (int b = 0; b < 2; ++b) acc[a][b] = (f32x4){0.f, 0.f, 0.f, 0.f};

        // staging: chunk c = wid*2+j covers rows [c*8, c*8+8) of the 64-row
        // tile; lane: row = c*8 + (lane>>3), 16B slot (lane&7).
        // swizzle: LDS slot k holds logical chunk k ^ (row&7); row&7 == lane>>3.
        const int r8  = lane >> 3;                    // 0..7
        const int swz = ((lane & 7) ^ r8) * 8;        // element offset in row
        const unsigned short* Ag0 = hvb  + (size_t)(bm + (wid * 2    ) * 8 + r8) * KHV + swz;
        const unsigned short* Ag1 = hvb  + (size_t)(bm + (wid * 2 + 1) * 8 + r8) * KHV + swz;
        const unsigned short* Bg0 = Winb + (size_t)(bn + (wid * 2    ) * 8 + r8) * KHV + swz;
        const unsigned short* Bg1 = Winb + (size_t)(bn + (wid * 2 + 1) * 8 + r8) * KHV + swz;

        auto stage = [&](int cb, int kt) {
            g2l16(Ag0 + kt, &sA[cb][(wid * 2    ) * 512]);
            g2l16(Ag1 + kt, &sA[cb][(wid * 2 + 1) * 512]);
            g2l16(Bg0 + kt, &sB[cb][(wid * 2    ) * 512]);
            g2l16(Bg1 + kt, &sB[cb][(wid * 2 + 1) * 512]);
        };
        auto compute = [&](int cb) {
            bf16x8 aF[2][2], bF[2][2];
#pragma unroll
            for (int kk = 0; kk < 2; ++kk) {
                const int ca = (((kk * 4 + quad) ^ (l15 & 7)) * 8);  // swizzled read
#pragma unroll
                for (int t = 0; t < 2; ++t) {
                    aF[kk][t] = *(const bf16x8*)&sA[cb][(wm * 32 + t * 16 + l15) * 64 + ca];
                    bF[kk][t] = *(const bf16x8*)&sB[cb][(wn * 32 + t * 16 + l15) * 64 + ca];
                }
            }
#pragma unroll
            for (int kk = 0; kk < 2; ++kk)
#pragma unroll
                for (int tm = 0; tm < 2; ++tm)
#pragma unroll
                    for (int tn = 0; tn < 2; ++tn)
                        acc[tm][tn] = __builtin_amdgcn_mfma_f32_16x16x32_bf16(
                            aF[kk][tm], bF[kk][tn], acc[tm][tn], 0, 0, 0);
        };

        stage(0, 0);
        __syncthreads();
        int cur = 0;
        for (int kt = 64; kt < KHV; kt += 64) {
            stage(cur ^ 1, kt);     // prefetch next tile (latency hidden below)
            compute(cur);
            __syncthreads();        // drains prefetch + all LDS reads
            cur ^= 1;
        }
        compute(cur);

#pragma unroll
        for (int tm = 0; tm < 2; ++tm)
#pragma unroll
            for (int tn = 0; tn < 2; ++tn) {
                const int n = bn + wn * 32 + tn * 16 + l15;
                const float bias = b_in[n];
#pragma unroll
                for (int r = 0; r < 4; ++r) {
                    const int m = bm + wm * 32 + tm * 16 + quad * 4 + r;
                    float x = acc[tm][tn][r] + bias;
                    float s2 = x * fsigmoid(x);
                    ctrl[(size_t)m * CDIM + n] = f2bf(s2);
                }
            }
    } else {
        // ----- gemm3: 128x128 tile, BK=32, linear LDS (64B rows: no conflict) -
        const int g3  = (int)(bidx / 3u) * 2 + (int)r3 - 1;   // 0..1023
        const int t3s = (g3 & 7) * 128 + (g3 >> 3);
        const int bm  = (t3s & 63) * 128;
        const int bn  = (t3s >> 6) * 128;

        f32x4 acc[4][4];
#pragma unroll
        for (int a = 0; a < 4; ++a)
#pragma unroll
            for (int b = 0; b < 4; ++b) acc[a][b] = (f32x4){0.f, 0.f, 0.f, 0.f};

        const int srow = lane >> 2;        // 0..15
        const int sk   = (lane & 3) * 8;   // k element offset
        const unsigned short* Ag0 = hvb  + (size_t)(bm + wid * 16 + srow) * KHV + sk;
        const unsigned short* Ag1 = hvb  + (size_t)(bm + (wid + 4) * 16 + srow) * KHV + sk;
        const unsigned short* Bg0 = Wmub + (size_t)(bn + wid * 16 + srow) * HDIM + sk;
        const unsigned short* Bg1 = Wmub + (size_t)(bn + (wid + 4) * 16 + srow) * HDIM + sk;

        auto stage = [&](int cb, int kt) {
            g2l16(Ag0 + kt, &sA[cb][(wid * 16) * 32]);
            g2l16(Ag1 + kt, &sA[cb][((wid + 4) * 16) * 32]);
            g2l16(Bg0 + kt, &sB[cb][(wid * 16) * 32]);
            g2l16(Bg1 + kt, &sB[cb][((wid + 4) * 16) * 32]);
        };
        auto compute = [&](int cb) {
            bf16x8 aF[4], bF[4];
#pragma unroll
            for (int t = 0; t < 4; ++t)
                aF[t] = *(const bf16x8*)&sA[cb][(wm * 64 + t * 16 + l15) * 32 + quad * 8];
#pragma unroll
            for (int t = 0; t < 4; ++t)
                bF[t] = *(const bf16x8*)&sB[cb][(wn * 64 + t * 16 + l15) * 32 + quad * 8];
#pragma unroll
            for (int tm = 0; tm < 4; ++tm)
#pragma unroll
                for (int tn = 0; tn < 4; ++tn)
                    acc[tm][tn] = __builtin_amdgcn_mfma_f32_16x16x32_bf16(
                        aF[tm], bF[tn], acc[tm][tn], 0, 0, 0);
        };

        stage(0, 0);
        __syncthreads();
        int cur = 0;
        for (int kt = 32; kt < HDIM; kt += 32) {
            stage(cur ^ 1, kt);
            compute(cur);
            __syncthreads();
            cur ^= 1;
        }
        compute(cur);

#pragma unroll
        for (int tm = 0; tm < 4; ++tm)
#pragma unroll
            for (int tn = 0; tn < 4; ++tn) {
                const int n = bn + wn * 64 + tn * 16 + l15;
                const float mub = mu[n];
#pragma unroll
                for (int r = 0; r < 4; ++r) {
                    const int m = bm + wm * 64 + tm * 16 + quad * 4 + r;
                    outmu[(size_t)m * HDIM + n] = acc[tm][tn][r] + mub;
                }
            }
    }
}

// ---------------- K3: ctrl_out (3 planes) + full fused elementwise -------
// Same 2-phase pipeline; K=256 -> 8 tiles (1 prologue + 7 pipelined).
__global__ __launch_bounds__(256, 4)
void k_gemm2(const unsigned short* __restrict__ A,
             const unsigned short* __restrict__ Bw,
             const float* __restrict__ b_out,
             const unsigned short* __restrict__ hv,   // bf16 [B, 4096]: h | v
             const float* __restrict__ mu_ctx,
             float* __restrict__ outp)
{
    __shared__ unsigned short sA[2][2048];       // 64x32 per buf
    __shared__ unsigned short sB[2][3][2048];
    const int tid  = threadIdx.x;
    const int wid  = tid >> 6;
    const int lane = tid & 63;
    const int quad = lane >> 4;
    const int l15  = lane & 15;
    const int wm   = wid >> 1, wn = wid & 1;
    const int bm   = blockIdx.x * 64;
    const int bn   = blockIdx.y * 64;
    const int srow = lane >> 2;
    const int sk   = (lane & 3) * 8;

    f32x4 acc[3][2][2];
#pragma unroll
    for (int p = 0; p < 3; ++p)
#pragma unroll
        for (int a = 0; a < 2; ++a)
#pragma unroll
            for (int b = 0; b < 2; ++b) acc[p][a][b] = (f32x4){0.f, 0.f, 0.f, 0.f};

    const unsigned short* Ag  = A + (size_t)(bm + wid * 16 + srow) * CDIM + sk;
    const unsigned short* Bg0 = Bw + (size_t)(0 * HDIM + bn + wid * 16 + srow) * CDIM + sk;
    const unsigned short* Bg1 = Bw + (size_t)(1 * HDIM + bn + wid * 16 + srow) * CDIM + sk;
    const unsigned short* Bg2 = Bw + (size_t)(2 * HDIM + bn + wid * 16 + srow) * CDIM + sk;

    auto stage = [&](int cb, int kt) {
        g2l16(Ag  + kt, &sA[cb][(wid * 16) * 32]);
        g2l16(Bg0 + kt, &sB[cb][0][(wid * 16) * 32]);
        g2l16(Bg1 + kt, &sB[cb][1][(wid * 16) * 32]);
        g2l16(Bg2 + kt, &sB[cb][2][(wid * 16) * 32]);
    };
    auto compute = [&](int cb) {
        bf16x8 aF[2], bF[3][2];
#pragma unroll
        for (int t = 0; t < 2; ++t)
            aF[t] = *(const bf16x8*)&sA[cb][(wm * 32 + t * 16 + l15) * 32 + quad * 8];
#pragma unroll
        for (int p = 0; p < 3; ++p)
#pragma unroll
            for (int t = 0; t < 2; ++t)
                bF[p][t] = *(const bf16x8*)&sB[cb][p][(wn * 32 + t * 16 + l15) * 32 + quad * 8];
#pragma unroll
        for (int p = 0; p < 3; ++p)
#pragma unroll
            for (int tm = 0; tm < 2; ++tm)
#pragma unroll
                for (int tn = 0; tn < 2; ++tn)
                    acc[p][tm][tn] = __builtin_amdgcn_mfma_f32_16x16x32_bf16(
                        aF[tm], bF[p][tn], acc[p][tm][tn], 0, 0, 0);
    };

    stage(0, 0);
    __syncthreads();
    int cur = 0;
    for (int kt = 32; kt < CDIM; kt += 32) {
        stage(cur ^ 1, kt);
        compute(cur);
        __syncthreads();
        cur ^= 1;
    }
    compute(cur);

#pragma unroll
    for (int tm = 0; tm < 2; ++tm)
#pragma unroll
        for (int tn = 0; tn < 2; ++tn) {
            const int i  = bn + wn * 32 + tn * 16 + l15;
            const float ba = b_out[i];
            const float bb = b_out[HDIM + i];
            const float bg = b_out[2 * HDIM + i];
#pragma unroll
            for (int r = 0; r < 4; ++r) {
                const int m = bm + wm * 32 + tm * 16 + quad * 4 + r;
                const size_t off = (size_t)m * HDIM + i;
                const float araw = acc[0][tm][tn][r] + ba;
                const float braw = acc[1][tm][tn][r] + bb;
                const float graw = acc[2][tm][tn][r] + bg;
                const float alpha = fsigmoid(araw);
                const float beta  = fminf(fsoftplus(braw), 2.f);
                const float gate  = fsigmoid(graw);
                const float hh = bf2f(hv[(size_t)m * KHV + i]);
                const float vv = bf2f(hv[(size_t)m * KHV + HDIM + i]);
                const float mm = mu_ctx[off];
                const float err = hh - mm;
                float vn = alpha * vv - beta * err;
                vn = fminf(fmaxf(vn, -10.f), 10.f);
                const float hn = hh + DT_C * gate * vn;
                outp[off] = hn;                              // h_next
                outp[(size_t)B_TOK * HDIM + off] = vn;       // v_next
            }
        }
}

extern "C" void kernel_launch(void* const* d_in, const int* in_sizes, int n_in,
                              void* d_out, int out_size, void* d_ws, size_t ws_size,
                              hipStream_t stream)
{
    const float* hp    = (const float*)d_in[0];
    const float* vp    = (const float*)d_in[1];
    const float* Win   = (const float*)d_in[2];
    const float* b_in  = (const float*)d_in[3];
    const float* Wout  = (const float*)d_in[4];
    const float* b_out = (const float*)d_in[5];
    const float* Wmu   = (const float*)d_in[6];
    const float* mu    = (const float*)d_in[7];
    float* outp = (float*)d_out;

    char* ws = (char*)d_ws;
    size_t off = 0;
    unsigned short* hv_b   = (unsigned short*)(ws + off); off += (size_t)B_TOK * KHV * 2;  // 64 MiB
    unsigned short* Wmu_b  = (unsigned short*)(ws + off); off += (size_t)HDIM * HDIM * 2;  //  8 MiB
    unsigned short* Wout_b = (unsigned short*)(ws + off); off += (size_t)N3H * CDIM * 2;   //  3 MiB
    unsigned short* Win_b  = (unsigned short*)(ws + off); off += (size_t)CDIM * KHV * 2;   //  2 MiB
    unsigned short* ctrl   = (unsigned short*)(ws + off); off += (size_t)B_TOK * CDIM * 2; //  4 MiB
    // total ws use ~81 MiB

    k_convert<<<dim3(4096), dim3(256), 0, stream>>>(
        hp, vp, Win, Wout, Wmu,
        (ushort4*)hv_b, (ushort4*)Wmu_b, (ushort4*)Wout_b, (ushort4*)Win_b);

    // fat kernel: gemm1 (512 blocks) + gemm3 (1024 blocks), b%3-interleaved
    k_mid<<<dim3(1536), dim3(256), 0, stream>>>(
        hv_b, Win_b, Wmu_b, b_in, mu, ctrl, outp + (size_t)2 * B_TOK * HDIM);

    k_gemm2<<<dim3(128, 32), dim3(256), 0, stream>>>(
        ctrl, Wout_b, b_out, hv_b,
        outp + (size_t)2 * B_TOK * HDIM, outp);
}

// Round 4
// 516.490 us; speedup vs baseline: 1.0453x; 1.0453x over previous
//
#include <hip/hip_runtime.h>
#include <cstdint>
#include <cstddef>

#define B_TOK 8192
#define HDIM  2048
#define CDIM  256
#define KHV   4096   // 2*H
#define N3H   6144   // 3*H
#define DT_C  0.1f

typedef __bf16 bf16x8 __attribute__((ext_vector_type(8)));
typedef float  f32x4  __attribute__((ext_vector_type(4)));

typedef __attribute__((address_space(1))) void as1_void;
typedef __attribute__((address_space(3))) void as3_void;

// counted vmcnt wait (T4). NEVER 0 inside the K-loop.
#define VM_WAIT(N) asm volatile("s_waitcnt vmcnt(" #N ")" ::: "memory")
// raw barrier is NOT a compiler memory fence: pin code motion around it.
#define SCHED_FENCE() __builtin_amdgcn_sched_barrier(0)

// async global->LDS, 16B per lane; LDS dst = wave-uniform base + lane*16
__device__ __forceinline__ void g2l16(const void* g, void* l) {
    __builtin_amdgcn_global_load_lds((as1_void*)(void*)(uintptr_t)(g),
                                     (as3_void*)l, 16, 0, 0);
}

__device__ __forceinline__ unsigned short f2bf(float f) {
    unsigned int u = __float_as_uint(f);
    u += 0x7fffu + ((u >> 16) & 1u);   // RNE
    return (unsigned short)(u >> 16);
}

__device__ __forceinline__ float bf2f(unsigned short s) {
    return __uint_as_float((unsigned int)s << 16);
}

// fast sigmoid: v_exp + v_rcp (no full-precision divide)
__device__ __forceinline__ float fsigmoid(float x) {
    return __builtin_amdgcn_rcpf(1.f + __expf(-x));
}
// fast softplus: max(x,0) + ln2*log2(1+exp(-|x|)), all native v_exp/v_log
__device__ __forceinline__ float fsoftplus(float x) {
    float t = __expf(-fabsf(x));
    return fmaxf(x, 0.f) + 0.69314718056f * __log2f(1.f + t);
}

// ---------------- K0: fp32 -> bf16 conversion (hv concat + weights) -------
__global__ void k_convert(const float* __restrict__ hp, const float* __restrict__ vp,
                          const float* __restrict__ Win, const float* __restrict__ Wout,
                          const float* __restrict__ Wmu,
                          ushort4* __restrict__ hv_b, ushort4* __restrict__ Wmu_b,
                          ushort4* __restrict__ Wout_b, ushort4* __restrict__ Win_b)
{
    const int HV_V   = B_TOK * KHV / 4;    // 8388608 vec4
    const int WMU_V  = HDIM * HDIM / 4;    // 1048576
    const int WOUT_V = N3H * CDIM / 4;     // 393216
    const int WIN_V  = CDIM * KHV / 4;     // 262144
    const int TOT    = HV_V + WMU_V + WOUT_V + WIN_V;
    for (int i = blockIdx.x * blockDim.x + threadIdx.x; i < TOT;
         i += gridDim.x * blockDim.x) {
        float4 x;
        ushort4* dst;
        if (i < HV_V) {
            int b  = i >> 10;          // row (4096/4 = 1024 vec4 per row)
            int c4 = i & 1023;
            x = (c4 < 512) ? ((const float4*)hp)[b * 512 + c4]
                           : ((const float4*)vp)[b * 512 + (c4 - 512)];
            dst = hv_b + i;
        } else if (i < HV_V + WMU_V) {
            int j = i - HV_V;
            x = ((const float4*)Wmu)[j];
            dst = Wmu_b + j;
        } else if (i < HV_V + WMU_V + WOUT_V) {
            int j = i - (HV_V + WMU_V);
            x = ((const float4*)Wout)[j];
            dst = Wout_b + j;
        } else {
            int j = i - (HV_V + WMU_V + WOUT_V);
            x = ((const float4*)Win)[j];
            dst = Win_b + j;
        }
        ushort4 o;
        o.x = __builtin_bit_cast(unsigned short, (__bf16)x.x);
        o.y = __builtin_bit_cast(unsigned short, (__bf16)x.y);
        o.z = __builtin_bit_cast(unsigned short, (__bf16)x.z);
        o.w = __builtin_bit_cast(unsigned short, (__bf16)x.w);
        *dst = o;
    }
}

// ---------------- K_mid: fat kernel = gemm1 (blocks 0..511) + gemm3 ------
// r1-verified tiles/layouts/swizzles. K-loop: counted-vmcnt 2-deep pipeline
// (T4) with sched_barrier(0) pinning around every raw s_barrier — a raw
// s_barrier is not an IR memory fence, so without pinning the compiler may
// hoist stage() above the buffer-release barrier (the r3 race) or hoist
// ds_reads above the fill barrier.
__global__ __launch_bounds__(256, 2)
void k_mid(const unsigned short* __restrict__ hvb,
           const unsigned short* __restrict__ Winb,
           const unsigned short* __restrict__ Wmub,
           const float* __restrict__ b_in,
           const float* __restrict__ mu,
           unsigned short* __restrict__ ctrl,
           float* __restrict__ outmu)
{
    __shared__ unsigned short sA[2][4096];   // 8KB/buf
    __shared__ unsigned short sB[2][4096];
    const int tid  = threadIdx.x;
    const int wid  = tid >> 6;
    const int lane = tid & 63;
    const int quad = lane >> 4;
    const int l15  = lane & 15;
    const int wm   = wid >> 1, wn = wid & 1;
    const int srow = lane >> 2;        // 0..15
    const int sk   = (lane & 3) * 8;   // k element offset 0/8/16/24

    if (blockIdx.x < 512) {
        // ----- gemm1: ctrl = silu(hv @ Win^T + b_in), 64x64, BK=32 -----
        const int s  = ((int)blockIdx.x & 7) * 64 + ((int)blockIdx.x >> 3);
        const int bm = (s >> 2) * 64;
        const int bn = (s & 3) * 64;

        f32x4 acc[2][2];
#pragma unroll
        for (int a = 0; a < 2; ++a)
#pragma unroll
            for (int b = 0; b < 2; ++b) acc[a][b] = (f32x4){0.f, 0.f, 0.f, 0.f};

        const unsigned short* Ag = hvb  + (size_t)(bm + wid * 16 + srow) * KHV + sk;
        const unsigned short* Bg = Winb + (size_t)(bn + wid * 16 + srow) * KHV + sk;

        auto stage = [&](int cb, int t) {   // 2 loads/thread
            g2l16(Ag + t * 32, &sA[cb][(wid * 16) * 32]);
            g2l16(Bg + t * 32, &sB[cb][(wid * 16) * 32]);
        };
        auto compute = [&](int cb) {
            bf16x8 aF[2], bF[2];
#pragma unroll
            for (int t = 0; t < 2; ++t)
                aF[t] = *(const bf16x8*)&sA[cb][(wm * 32 + t * 16 + l15) * 32 + quad * 8];
#pragma unroll
            for (int t = 0; t < 2; ++t)
                bF[t] = *(const bf16x8*)&sB[cb][(wn * 32 + t * 16 + l15) * 32 + quad * 8];
#pragma unroll
            for (int tm = 0; tm < 2; ++tm)
#pragma unroll
                for (int tn = 0; tn < 2; ++tn)
                    acc[tm][tn] = __builtin_amdgcn_mfma_f32_16x16x32_bf16(
                        aF[tm], bF[tn], acc[tm][tn], 0, 0, 0);
        };

        const int nt = KHV / 32;    // 128
        stage(0, 0);
        stage(1, 1);                // 4 loads outstanding
        for (int t = 0; t < nt - 1; ++t) {
            VM_WAIT(2);                         // own tile-t loads landed
            __builtin_amdgcn_s_barrier();       // => ALL waves' tile-t landed
            SCHED_FENCE();                      // no ds_read hoists above fill
            compute(t & 1);
            SCHED_FENCE();                      // no ds_read sinks below release
            __builtin_amdgcn_s_barrier();       // all waves done reading buf
            SCHED_FENCE();                      // no stage hoists above release
            if (t + 2 < nt) stage(t & 1, t + 2);
        }
        VM_WAIT(0);
        __builtin_amdgcn_s_barrier();
        SCHED_FENCE();
        compute((nt - 1) & 1);

#pragma unroll
        for (int tm = 0; tm < 2; ++tm)
#pragma unroll
            for (int tn = 0; tn < 2; ++tn) {
                const int n = bn + wn * 32 + tn * 16 + l15;
                const float bias = b_in[n];
#pragma unroll
                for (int r = 0; r < 4; ++r) {
                    const int m = bm + wm * 32 + tm * 16 + quad * 4 + r;
                    float x = acc[tm][tn][r] + bias;
                    float s2 = x * fsigmoid(x);
                    ctrl[(size_t)m * CDIM + n] = f2bf(s2);
                }
            }
    } else {
        // ----- gemm3: mu_ctx = mu + h @ Wmu^T, 128x128, BK=32 -----
        const int t3  = (int)blockIdx.x - 512;
        const int t3s = (t3 & 7) * 128 + (t3 >> 3);
        const int bm  = (t3s & 63) * 128;
        const int bn  = (t3s >> 6) * 128;

        f32x4 acc[4][4];
#pragma unroll
        for (int a = 0; a < 4; ++a)
#pragma unroll
            for (int b = 0; b < 4; ++b) acc[a][b] = (f32x4){0.f, 0.f, 0.f, 0.f};

        const unsigned short* Ag0 = hvb  + (size_t)(bm + wid * 16 + srow) * KHV + sk;
        const unsigned short* Ag1 = hvb  + (size_t)(bm + (wid + 4) * 16 + srow) * KHV + sk;
        const unsigned short* Bg0 = Wmub + (size_t)(bn + wid * 16 + srow) * HDIM + sk;
        const unsigned short* Bg1 = Wmub + (size_t)(bn + (wid + 4) * 16 + srow) * HDIM + sk;

        auto stage = [&](int cb, int t) {   // 4 loads/thread
            g2l16(Ag0 + t * 32, &sA[cb][(wid * 16) * 32]);
            g2l16(Ag1 + t * 32, &sA[cb][((wid + 4) * 16) * 32]);
            g2l16(Bg0 + t * 32, &sB[cb][(wid * 16) * 32]);
            g2l16(Bg1 + t * 32, &sB[cb][((wid + 4) * 16) * 32]);
        };
        auto compute = [&](int cb) {
            bf16x8 aF[4], bF[4];
#pragma unroll
            for (int t = 0; t < 4; ++t)
                aF[t] = *(const bf16x8*)&sA[cb][(wm * 64 + t * 16 + l15) * 32 + quad * 8];
#pragma unroll
            for (int t = 0; t < 4; ++t)
                bF[t] = *(const bf16x8*)&sB[cb][(wn * 64 + t * 16 + l15) * 32 + quad * 8];
#pragma unroll
            for (int tm = 0; tm < 4; ++tm)
#pragma unroll
                for (int tn = 0; tn < 4; ++tn)
                    acc[tm][tn] = __builtin_amdgcn_mfma_f32_16x16x32_bf16(
                        aF[tm], bF[tn], acc[tm][tn], 0, 0, 0);
        };

        const int nt = HDIM / 32;   // 64
        stage(0, 0);
        stage(1, 1);                // 8 loads outstanding
        for (int t = 0; t < nt - 1; ++t) {
            VM_WAIT(4);                         // own tile-t loads landed
            __builtin_amdgcn_s_barrier();       // => ALL waves' tile-t landed
            SCHED_FENCE();
            compute(t & 1);
            SCHED_FENCE();
            __builtin_amdgcn_s_barrier();       // all waves done reading buf
            SCHED_FENCE();
            if (t + 2 < nt) stage(t & 1, t + 2);
        }
        VM_WAIT(0);
        __builtin_amdgcn_s_barrier();
        SCHED_FENCE();
        compute((nt - 1) & 1);

#pragma unroll
        for (int tm = 0; tm < 4; ++tm)
#pragma unroll
            for (int tn = 0; tn < 4; ++tn) {
                const int n = bn + wn * 64 + tn * 16 + l15;
                const float mub = mu[n];
#pragma unroll
                for (int r = 0; r < 4; ++r) {
                    const int m = bm + wm * 64 + tm * 16 + quad * 4 + r;
                    outmu[(size_t)m * HDIM + n] = acc[tm][tn][r] + mub;
                }
            }
    }
}

// ---------------- K3: ctrl_out (3 planes) + full fused elementwise -------
// r1-VERIFIED structure (single buffer, __syncthreads pair) — de-risked.
__global__ __launch_bounds__(256, 4)
void k_gemm2(const unsigned short* __restrict__ A,
             const unsigned short* __restrict__ Bw,
             const float* __restrict__ b_out,
             const unsigned short* __restrict__ hv,   // bf16 [B, 4096]: h | v
             const float* __restrict__ mu_ctx,
             float* __restrict__ outp)
{
    __shared__ unsigned short sA[64 * 32];
    __shared__ unsigned short sB[3][64 * 32];
    const int tid  = threadIdx.x;
    const int wid  = tid >> 6;
    const int lane = tid & 63;
    const int quad = lane >> 4;
    const int l15  = lane & 15;
    const int wm   = wid >> 1, wn = wid & 1;
    const int bm   = blockIdx.x * 64;
    const int bn   = blockIdx.y * 64;
    const int srow = lane >> 2;
    const int sk   = (lane & 3) * 8;

    f32x4 acc[3][2][2];
#pragma unroll
    for (int p = 0; p < 3; ++p)
#pragma unroll
        for (int a = 0; a < 2; ++a)
#pragma unroll
            for (int b = 0; b < 2; ++b) acc[p][a][b] = (f32x4){0.f, 0.f, 0.f, 0.f};

    const unsigned short* Ag  = A + (size_t)(bm + wid * 16 + srow) * CDIM + sk;
    const unsigned short* Bg0 = Bw + (size_t)(0 * HDIM + bn + wid * 16 + srow) * CDIM + sk;
    const unsigned short* Bg1 = Bw + (size_t)(1 * HDIM + bn + wid * 16 + srow) * CDIM + sk;
    const unsigned short* Bg2 = Bw + (size_t)(2 * HDIM + bn + wid * 16 + srow) * CDIM + sk;
    unsigned short* lA  = &sA[(wid * 16) * 32];
    unsigned short* lB0 = &sB[0][(wid * 16) * 32];
    unsigned short* lB1 = &sB[1][(wid * 16) * 32];
    unsigned short* lB2 = &sB[2][(wid * 16) * 32];

    for (int kt = 0; kt < CDIM; kt += 32) {
        g2l16(Ag  + kt, lA);
        g2l16(Bg0 + kt, lB0);
        g2l16(Bg1 + kt, lB1);
        g2l16(Bg2 + kt, lB2);
        __syncthreads();
        bf16x8 aF[2], bF[3][2];
#pragma unroll
        for (int t = 0; t < 2; ++t)
            aF[t] = *(const bf16x8*)&sA[(wm * 32 + t * 16 + l15) * 32 + quad * 8];
#pragma unroll
        for (int p = 0; p < 3; ++p)
#pragma unroll
            for (int t = 0; t < 2; ++t)
                bF[p][t] = *(const bf16x8*)&sB[p][(wn * 32 + t * 16 + l15) * 32 + quad * 8];
#pragma unroll
        for (int p = 0; p < 3; ++p)
#pragma unroll
            for (int tm = 0; tm < 2; ++tm)
#pragma unroll
                for (int tn = 0; tn < 2; ++tn)
                    acc[p][tm][tn] = __builtin_amdgcn_mfma_f32_16x16x32_bf16(
                        aF[tm], bF[p][tn], acc[p][tm][tn], 0, 0, 0);
        __syncthreads();
    }

#pragma unroll
    for (int tm = 0; tm < 2; ++tm)
#pragma unroll
        for (int tn = 0; tn < 2; ++tn) {
            const int i  = bn + wn * 32 + tn * 16 + l15;
            const float ba = b_out[i];
            const float bb = b_out[HDIM + i];
            const float bg = b_out[2 * HDIM + i];
#pragma unroll
            for (int r = 0; r < 4; ++r) {
                const int m = bm + wm * 32 + tm * 16 + quad * 4 + r;
                const size_t off = (size_t)m * HDIM + i;
                const float araw = acc[0][tm][tn][r] + ba;
                const float braw = acc[1][tm][tn][r] + bb;
                const float graw = acc[2][tm][tn][r] + bg;
                const float alpha = fsigmoid(araw);
                const float beta  = fminf(fsoftplus(braw), 2.f);
                const float gate  = fsigmoid(graw);
                const float hh = bf2f(hv[(size_t)m * KHV + i]);
                const float vv = bf2f(hv[(size_t)m * KHV + HDIM + i]);
                const float mm = mu_ctx[off];
                const float err = hh - mm;
                float vn = alpha * vv - beta * err;
                vn = fminf(fmaxf(vn, -10.f), 10.f);
                const float hn = hh + DT_C * gate * vn;
                outp[off] = hn;                              // h_next
                outp[(size_t)B_TOK * HDIM + off] = vn;       // v_next
            }
        }
}

extern "C" void kernel_launch(void* const* d_in, const int* in_sizes, int n_in,
                              void* d_out, int out_size, void* d_ws, size_t ws_size,
                              hipStream_t stream)
{
    const float* hp    = (const float*)d_in[0];
    const float* vp    = (const float*)d_in[1];
    const float* Win   = (const float*)d_in[2];
    const float* b_in  = (const float*)d_in[3];
    const float* Wout  = (const float*)d_in[4];
    const float* b_out = (const float*)d_in[5];
    const float* Wmu   = (const float*)d_in[6];
    const float* mu    = (const float*)d_in[7];
    float* outp = (float*)d_out;

    char* ws = (char*)d_ws;
    size_t off = 0;
    unsigned short* hv_b   = (unsigned short*)(ws + off); off += (size_t)B_TOK * KHV * 2;  // 64 MiB
    unsigned short* Wmu_b  = (unsigned short*)(ws + off); off += (size_t)HDIM * HDIM * 2;  //  8 MiB
    unsigned short* Wout_b = (unsigned short*)(ws + off); off += (size_t)N3H * CDIM * 2;   //  3 MiB
    unsigned short* Win_b  = (unsigned short*)(ws + off); off += (size_t)CDIM * KHV * 2;   //  2 MiB
    unsigned short* ctrl   = (unsigned short*)(ws + off); off += (size_t)B_TOK * CDIM * 2; //  4 MiB
    // total ws use ~81 MiB

    k_convert<<<dim3(4096), dim3(256), 0, stream>>>(
        hp, vp, Win, Wout, Wmu,
        (ushort4*)hv_b, (ushort4*)Wmu_b, (ushort4*)Wout_b, (ushort4*)Win_b);

    // fat kernel: gemm1 (512 blocks) + gemm3 (1024 blocks)
    k_mid<<<dim3(1536), dim3(256), 0, stream>>>(
        hv_b, Win_b, Wmu_b, b_in, mu, ctrl, outp + (size_t)2 * B_TOK * HDIM);

    k_gemm2<<<dim3(128, 32), dim3(256), 0, stream>>>(
        ctrl, Wout_b, b_out, hv_b,
        outp + (size_t)2 * B_TOK * HDIM, outp);
}